// Round 5
// baseline (257.462 us; speedup 1.0000x reference)
//
#include <hip/hip_runtime.h>
#include <float.h>

#define NROWS 65536
#define DK 256
#define NCODES 1024
#define BLK_ROWS 32
#define NBLK (NROWS / BLK_ROWS)
#define FLAG_CAP 16384
#define FLAG2_CAP 4096
// scaled-distance margins: d_s = (||e||^2 + 384 - 2 x.e) * 2^-6; sigma_diff ~ 1.9e-4 scaled
#define MARGIN_A 0.0025f   // ~13 sigma: top-2 exact rescore set (~6000 rows)
#define MARGIN_B 0.0016f   // ~8.5 sigma on 3rd-gap: full fp64 scan set (~400 rows)

#define LOSS_OFF 16777216
#define IDX_OFF  16777217

// ---------------- ws layout (bytes) ----------------
#define WS_FLAG1   0        // int
#define WS_FLAG2   4        // int
#define WS_LOSSP   8        // double[64]
#define WS_ENORMD  520      // double[1024]
#define WS_ENORMF  8712     // float[1024]  (scaled: (norm+384)*2^-6)
#define WS_FROWS   12808    // int[FLAG_CAP]  rec = row | (c2<<16)
#define WS_F2ROWS  78344    // int[FLAG2_CAP] rows
#define WS_IDX     94728    // int[65536]
#define WS_EHI     356872   // fp16[1024*256] frag-swizzled (512 KB); total ~881 KB

typedef _Float16 f16x8 __attribute__((ext_vector_type(8)));
typedef float f32x4 __attribute__((ext_vector_type(4)));
typedef unsigned int uint32;

__device__ __forceinline__ uint32 packh2(float a, float b) {
  return (uint32)__builtin_bit_cast(unsigned short, (_Float16)a) |
         ((uint32)__builtin_bit_cast(unsigned short, (_Float16)b) << 16);
}

// ---- init: counters, fp64 E norms, scaled fp32 norms, E -> f16 swizzled ----
__global__ __launch_bounds__(256) void init_kernel(
    const float* __restrict__ E, double* __restrict__ enorm_d,
    float* __restrict__ enorm_f, uint4* __restrict__ Ehi,
    int* __restrict__ flag1, int* __restrict__ flag2,
    double* __restrict__ loss_part) {
  const int t = threadIdx.x;
  const int c = blockIdx.x * 8 + (t >> 5);
  const int g = t & 31;  // 8-element group within the code row
  if (blockIdx.x == 0) {
    if (t == 0) *flag1 = 0;
    if (t == 1) *flag2 = 0;
    if (t < 64) loss_part[t] = 0.0;
  }
  const float4* er4 = (const float4*)(E + (size_t)c * DK);
  const float4 va = er4[g * 2];
  const float4 vb = er4[g * 2 + 1];
  double s = (double)va.x * va.x + (double)va.y * va.y + (double)va.z * va.z + (double)va.w * va.w
           + (double)vb.x * vb.x + (double)vb.y * vb.y + (double)vb.z * vb.z + (double)vb.w * vb.w;
  uint4 h;
  h.x = packh2(va.x, va.y);
  h.y = packh2(va.z, va.w);
  h.z = packh2(vb.x, vb.y);
  h.w = packh2(vb.z, vb.w);
  const int ctg = c >> 8, cga = (c >> 4) & 15, col = c & 15;
  const int kc = g >> 2, quad = g & 3;  // ks = kc
  Ehi[((size_t)(ctg * 128 + kc * 16 + cga)) * 64 + (size_t)(quad * 16 + col)] = h;
  #pragma unroll
  for (int m = 1; m < 32; m <<= 1) s += __shfl_xor(s, m, 64);
  if (g == 0) {
    enorm_d[c] = s;
    enorm_f[c] = (float)((s + 384.0) * 0.015625);  // scaled + biased, exact pow2 scale
  }
}

// ---- phase 1 (fused): f16 MFMA distances + top-3 argmin + gather/loss tail ----
// 256 thr / 4 waves, 32 rows x all 1024 codes per block, 4 blocks/CU.
// A resident in 16 KB LDS (frag order); B global->VGPR with depth-1 prefetch.
__global__ __launch_bounds__(256, 4) void dist_fused(
    const float* __restrict__ X, const uint4* __restrict__ Ehi,
    const float* __restrict__ E, const float* __restrict__ enorm_f,
    int* __restrict__ idx_ws, int* __restrict__ flag1, int* __restrict__ flag_rows,
    int* __restrict__ flag2, int* __restrict__ flag2_rows,
    float* __restrict__ out, double* __restrict__ loss_part) {
  __shared__ __attribute__((aligned(16))) char lds[16384];
  __shared__ int idxs[BLK_ROWS];
  __shared__ double wsum[4];
  const int tid = threadIdx.x;
  const int lane = tid & 63;
  const int wid = tid >> 6;
  const int col = lane & 15;
  const int rowBase = blockIdx.x * BLK_ROWS;

  // stage A: 32 rows x 256 k, fp32 -> f16 RNE, fragment order
  {
    const float4* X4 = (const float4*)X + (size_t)rowBase * 64;
    #pragma unroll
    for (int i = 0; i < 8; ++i) {
      const int f4 = i * 256 + tid;
      const int row = f4 >> 6;
      const int k0 = (f4 & 63) << 2;
      const float4 v = X4[f4];
      uint2 p;
      p.x = packh2(v.x, v.y);
      p.y = packh2(v.z, v.w);
      const int off = (((row >> 4) * 8 + (k0 >> 5)) * 64 + ((k0 >> 3) & 3) * 16 + (row & 15)) * 16
                      + ((k0 >> 2) & 1) * 8;
      *(uint2*)(lds + off) = p;
    }
  }
  __syncthreads();

  // packed top-3 per row (8 rows/lane); wave-local idx in low 8 bits of rv1/rv2
  float rv1[8], rv2[8], rv3[8];
  #pragma unroll
  for (int i = 0; i < 8; ++i) { rv1[i] = FLT_MAX; rv2[i] = FLT_MAX; rv3[i] = FLT_MAX; }

  for (int ctg = 0; ctg < 4; ++ctg) {
    f32x4 acc[2][4];
    #pragma unroll
    for (int rg = 0; rg < 2; ++rg)
      #pragma unroll
      for (int cg = 0; cg < 4; ++cg) acc[rg][cg] = (f32x4){0.f, 0.f, 0.f, 0.f};

    const uint4* Bp = Ehi + ((size_t)(ctg * 128 + wid * 4)) * 64 + (size_t)lane;
    f16x8 bcur[4];
    #pragma unroll
    for (int cg = 0; cg < 4; ++cg) bcur[cg] = *(const f16x8*)&Bp[cg * 64];
    #pragma unroll
    for (int ks = 0; ks < 8; ++ks) {
      f16x8 bnxt[4];
      if (ks < 7) {
        #pragma unroll
        for (int cg = 0; cg < 4; ++cg)
          bnxt[cg] = *(const f16x8*)&Bp[(ks + 1) * 1024 + cg * 64];
      }
      f16x8 a[2];
      #pragma unroll
      for (int rg = 0; rg < 2; ++rg)
        a[rg] = *(const f16x8*)(lds + ((rg * 8 + ks) * 64 + lane) * 16);
      #pragma unroll
      for (int rg = 0; rg < 2; ++rg)
        #pragma unroll
        for (int cg = 0; cg < 4; ++cg)
          acc[rg][cg] = __builtin_amdgcn_mfma_f32_16x16x32_f16(a[rg], bcur[cg], acc[rg][cg], 0, 0, 0);
      if (ks < 7) {
        #pragma unroll
        for (int cg = 0; cg < 4; ++cg) bcur[cg] = bnxt[cg];
      }
    }
    // epilogue: scaled d; insert into per-lane top-3 (min network)
    #pragma unroll
    for (int cg = 0; cg < 4; ++cg) {
      const int code = ctg * 256 + wid * 64 + cg * 16 + col;
      const float en = enorm_f[code];  // already (norm+384)*2^-6
      const uint32 li = (uint32)((ctg << 6) | (cg << 4) | col);
      #pragma unroll
      for (int rg = 0; rg < 2; ++rg)
        #pragma unroll
        for (int reg = 0; reg < 4; ++reg) {
          const int i = rg * 4 + reg;
          const float d = fmaf(acc[rg][cg][reg], -0.03125f, en);
          const float p = __builtin_bit_cast(float,
              (__builtin_bit_cast(uint32, d) & 0xFFFFFF00u) | li);
          const float t1 = fmaxf(rv1[i], p);
          rv1[i] = fminf(rv1[i], p);
          const float t2 = fmaxf(rv2[i], t1);
          rv2[i] = fminf(rv2[i], t1);
          rv3[i] = fminf(rv3[i], t2);
        }
    }
  }

  // merge 16 cols within each quad: sorted-triple merge network
  #pragma unroll
  for (int i = 0; i < 8; ++i) {
    #pragma unroll
    for (int m = 1; m < 16; m <<= 1) {
      const float o1 = __shfl_xor(rv1[i], m, 64);
      const float o2 = __shfl_xor(rv2[i], m, 64);
      const float o3 = __shfl_xor(rv3[i], m, 64);
      const float hi = fmaxf(rv1[i], o1);
      const float n1 = fminf(rv1[i], o1);
      const float c = fminf(rv2[i], o2);
      const float d = fmaxf(rv2[i], o2);
      rv1[i] = n1;
      rv2[i] = fminf(hi, c);
      rv3[i] = fminf(fminf(fmaxf(hi, c), d), fminf(rv3[i], o3));
    }
  }

  __syncthreads();  // A region dead; reuse for merge buffer
  uint32* M = (uint32*)lds;  // [row 32][wave 4][5] = {v1, gi1, v2, gi2, v3}
  if (col == 0) {
    const int quad = lane >> 4;
    #pragma unroll
    for (int i = 0; i < 8; ++i) {
      const int row = (i >> 2) * 16 + quad * 4 + (i & 3);
      const uint32 u1 = __builtin_bit_cast(uint32, rv1[i]);
      const uint32 u2 = __builtin_bit_cast(uint32, rv2[i]);
      const uint32 li1 = u1 & 255u, li2 = u2 & 255u;
      uint32* Mr = &M[(row * 4 + wid) * 5];
      Mr[0] = u1;
      Mr[1] = (uint32)(((li1 >> 6) & 3) * 256 + wid * 64 + ((li1 >> 4) & 3) * 16 + (li1 & 15));
      Mr[2] = u2;
      Mr[3] = (uint32)(((li2 >> 6) & 3) * 256 + wid * 64 + ((li2 >> 4) & 3) * 16 + (li2 & 15));
      Mr[4] = __builtin_bit_cast(uint32, rv3[i]);
    }
  }
  __syncthreads();
  if (tid < BLK_ROWS) {
    float b1 = FLT_MAX, b2 = FLT_MAX, b3 = FLT_MAX;
    int bi1 = 0, bi2 = 0;
    #pragma unroll
    for (int w = 0; w < 4; ++w) {
      const uint32* Mr = &M[(tid * 4 + w) * 5];
      const float v1 = __builtin_bit_cast(float, Mr[0]);
      const float v2 = __builtin_bit_cast(float, Mr[2]);
      const float v3 = __builtin_bit_cast(float, Mr[4]);
      const int g1 = (int)Mr[1], g2 = (int)Mr[3];
      if (v1 < b1) { b3 = b2; b2 = b1; bi2 = bi1; b1 = v1; bi1 = g1; }
      else if (v1 < b2) { b3 = b2; b2 = v1; bi2 = g1; }
      else b3 = fminf(b3, v1);
      if (v2 < b1) { b3 = b2; b2 = b1; bi2 = bi1; b1 = v2; bi1 = g2; }
      else if (v2 < b2) { b3 = b2; b2 = v2; bi2 = g2; }
      else b3 = fminf(b3, v2);
      b3 = fminf(b3, v3);  // v3 >= own wave's v1,v2 already inserted
    }
    const int row = rowBase + tid;
    idxs[tid] = bi1;
    idx_ws[row] = bi1;
    out[IDX_OFF + row] = (float)bi1;
    const float q1 = __builtin_bit_cast(float, __builtin_bit_cast(uint32, b1) & 0xFFFFFF00u);
    const float q2 = __builtin_bit_cast(float, __builtin_bit_cast(uint32, b2) & 0xFFFFFF00u);
    const float q3 = __builtin_bit_cast(float, __builtin_bit_cast(uint32, b3) & 0xFFFFFF00u);
    if (q2 - q1 < MARGIN_A) {
      const int p = atomicAdd(flag1, 1);
      if (p < FLAG_CAP) flag_rows[p] = row | (bi2 << 16);
    }
    if (q3 - q1 < MARGIN_B) {
      const int p = atomicAdd(flag2, 1);
      if (p < FLAG2_CAP) flag2_rows[p] = row;
    }
  }
  __syncthreads();

  // fused tail: gather quantized, write, fp64 loss partial (provisional idx)
  const int rsub = tid >> 6, c4 = tid & 63;
  double ls = 0.0;
  #pragma unroll 4
  for (int i = 0; i < 8; ++i) {
    const int rl = i * 4 + rsub;
    const int row = rowBase + rl;
    const int idx = idxs[rl];
    const float4 q = ((const float4*)E)[(size_t)idx * 64 + c4];
    const float4 x = ((const float4*)X)[(size_t)row * 64 + c4];
    ((float4*)out)[(size_t)row * 64 + c4] = q;
    const double d0 = (double)q.x - (double)x.x;
    const double d1 = (double)q.y - (double)x.y;
    const double d2 = (double)q.z - (double)x.z;
    const double d3 = (double)q.w - (double)x.w;
    ls += d0 * d0 + d1 * d1 + d2 * d2 + d3 * d3;
  }
  #pragma unroll
  for (int o = 32; o > 0; o >>= 1) ls += __shfl_down(ls, o, 64);
  if ((tid & 63) == 0) wsum[tid >> 6] = ls;
  __syncthreads();
  if (tid == 0)
    atomicAdd(&loss_part[blockIdx.x & 63], wsum[0] + wsum[1] + wsum[2] + wsum[3]);
}

// ---- fixupA: exact fp64 rescore of {c1, c2} for flagA rows (1 row/wave) ----
__global__ __launch_bounds__(256) void fixupA(
    const float* __restrict__ X, const float* __restrict__ E,
    const double* __restrict__ enorm_d, const int* __restrict__ flag1,
    const int* __restrict__ flag_rows, int* __restrict__ idx_ws,
    float* __restrict__ out, double* __restrict__ loss_part) {
  int cnt = *flag1;
  if (cnt > FLAG_CAP) cnt = FLAG_CAP;
  const int r = blockIdx.x * 4 + (threadIdx.x >> 6);
  if (r >= cnt) return;
  const int lane = threadIdx.x & 63;
  const uint32 rec = (uint32)flag_rows[r];
  const int row = (int)(rec & 0xFFFFu);
  const int c2 = (int)(rec >> 16);
  const int c1 = idx_ws[row];
  const float4 xv = ((const float4*)X)[(size_t)row * 64 + lane];
  const float4 e1 = ((const float4*)E)[(size_t)c1 * 64 + lane];
  const float4 e2 = ((const float4*)E)[(size_t)c2 * 64 + lane];
  double s1 = (double)xv.x * e1.x + (double)xv.y * e1.y + (double)xv.z * e1.z + (double)xv.w * e1.w;
  double s2 = (double)xv.x * e2.x + (double)xv.y * e2.y + (double)xv.z * e2.z + (double)xv.w * e2.w;
  #pragma unroll
  for (int o = 32; o > 0; o >>= 1) {
    s1 += __shfl_down(s1, o, 64);
    s2 += __shfl_down(s2, o, 64);
  }
  s1 = __shfl(s1, 0, 64);
  s2 = __shfl(s2, 0, 64);
  const double d1 = enorm_d[c1] - 2.0 * s1;
  const double d2 = enorm_d[c2] - 2.0 * s2;
  if (d2 < d1 || (d2 == d1 && c2 < c1)) {
    ((float4*)out)[(size_t)row * 64 + lane] = e2;
    if (lane == 0) {
      idx_ws[row] = c2;
      out[IDX_OFF + row] = (float)c2;
      atomicAdd(&loss_part[row & 63], d2 - d1);
    }
  }
}

// ---- fixup64: full fp64 scan for flagB rows (1 row/block) ----
__global__ __launch_bounds__(256) void fixup64(
    const float* __restrict__ X, const float* __restrict__ E,
    const double* __restrict__ enorm_d, const int* __restrict__ flag2,
    const int* __restrict__ flag2_rows, int* __restrict__ idx_ws,
    float* __restrict__ out, double* __restrict__ loss_part) {
  __shared__ float xs[256];
  __shared__ double rv[256];
  __shared__ int ri[256];
  __shared__ double dold_s;
  __shared__ int old_s;
  int cnt = *flag2;
  if (cnt > FLAG2_CAP) cnt = FLAG2_CAP;
  if ((int)blockIdx.x >= cnt) return;
  const int row = flag2_rows[blockIdx.x];
  const int t = threadIdx.x;
  if (t == 0) old_s = idx_ws[row];
  xs[t] = X[(size_t)row * DK + t];
  __syncthreads();
  const int old = old_s;
  double best = 1e300;
  int bi = 0x7fffffff;
  double dold = 0.0;
  #pragma unroll
  for (int cc = 0; cc < 4; ++cc) {
    const int c = cc * 256 + t;  // ascending per thread => '<' keeps lowest
    const float4* E4 = (const float4*)(E + (size_t)c * DK);
    double s = 0.0;
    #pragma unroll 4
    for (int q = 0; q < 64; ++q) {
      const float4 ev = E4[q];
      const float4 xq = ((const float4*)xs)[q];
      s += (double)ev.x * xq.x + (double)ev.y * xq.y + (double)ev.z * xq.z + (double)ev.w * xq.w;
    }
    const double d = enorm_d[c] - 2.0 * s;
    if (d < best) { best = d; bi = c; }
    if (c == old) dold = d;
  }
  rv[t] = best;
  ri[t] = bi;
  if (t == (old & 255)) dold_s = dold;  // owner thread of old's residue class, cc = old>>8
  __syncthreads();
  for (int off = 128; off > 0; off >>= 1) {
    if (t < off) {
      const double ov = rv[t + off];
      const int oi = ri[t + off];
      if (ov < rv[t] || (ov == rv[t] && oi < ri[t])) { rv[t] = ov; ri[t] = oi; }
    }
    __syncthreads();
  }
  const int newi = ri[0];
  if (newi != old) {
    out[(size_t)row * DK + t] = E[(size_t)newi * DK + t];
    if (t == 0) {
      idx_ws[row] = newi;
      out[IDX_OFF + row] = (float)newi;
      atomicAdd(&loss_part[row & 63], rv[0] - dold_s);
    }
  }
}

__global__ __launch_bounds__(64) void finalize(
    const double* __restrict__ loss_part, float* __restrict__ out) {
  double v = loss_part[threadIdx.x];
  for (int o = 32; o > 0; o >>= 1) v += __shfl_down(v, o, 64);
  if (threadIdx.x == 0) out[LOSS_OFF] = (float)(v / 16777216.0);
}

extern "C" void kernel_launch(void* const* d_in, const int* in_sizes, int n_in,
                              void* d_out, int out_size, void* d_ws, size_t ws_size,
                              hipStream_t stream) {
  const float* X = (const float*)d_in[0];  // [65536, 256]
  const float* E = (const float*)d_in[1];  // [1024, 256]
  float* out = (float*)d_out;
  char* ws = (char*)d_ws;

  int*    flag1      = (int*)(ws + WS_FLAG1);
  int*    flag2      = (int*)(ws + WS_FLAG2);
  double* loss_part  = (double*)(ws + WS_LOSSP);
  double* enorm_d    = (double*)(ws + WS_ENORMD);
  float*  enorm_f    = (float*)(ws + WS_ENORMF);
  int*    flag_rows  = (int*)(ws + WS_FROWS);
  int*    flag2_rows = (int*)(ws + WS_F2ROWS);
  int*    idx_ws     = (int*)(ws + WS_IDX);
  uint4*  Ehi        = (uint4*)(ws + WS_EHI);

  hipLaunchKernelGGL(init_kernel, dim3(128), dim3(256), 0, stream,
                     E, enorm_d, enorm_f, Ehi, flag1, flag2, loss_part);
  hipLaunchKernelGGL(dist_fused, dim3(NBLK), dim3(256), 0, stream,
                     X, Ehi, E, enorm_f, idx_ws, flag1, flag_rows,
                     flag2, flag2_rows, out, loss_part);
  hipLaunchKernelGGL(fixupA, dim3(FLAG_CAP / 4), dim3(256), 0, stream,
                     X, E, enorm_d, flag1, flag_rows, idx_ws, out, loss_part);
  hipLaunchKernelGGL(fixup64, dim3(FLAG2_CAP), dim3(256), 0, stream,
                     X, E, enorm_d, flag2, flag2_rows, idx_ws, out, loss_part);
  hipLaunchKernelGGL(finalize, dim3(1), dim3(64), 0, stream, loss_part, out);
}